// Round 4
// baseline (155.102 us; speedup 1.0000x reference)
//
#include <hip/hip_runtime.h>

// Constrained sparsemax: p = clip(z - tau, 0, u), tau s.t. sum p = 1.
// Wave-per-row, 2 rows per wave (software-pipelined loads).
// Phase 1 (f32): Newton with f via med3 (3 VALU/elem) and count C via
//   __ballot/__popcll (scalar pipe, wave-uniform, no shuffle reduce).
//   Candidate tau' = tau + (f-1)/C  ==  (S-1)/C, bracket-safeguarded.
// Phase 2 (f64): same iteration in f64 -> exact root; regions/tau/val from it.
// All reduces are __shfl_xor butterflies (bit-identical across lanes).

__device__ __forceinline__ float wred(float v) {
  #pragma unroll
  for (int m = 32; m; m >>= 1) v += __shfl_xor(v, m);
  return v;
}
__device__ __forceinline__ double wredd(double v) {
  #pragma unroll
  for (int m = 32; m; m >>= 1) v += __shfl_xor(v, m);
  return v;
}

__device__ __forceinline__ double solve_tau(const float zf[16], const float uf[16]) {
  // bracket [lo,hi]: f(lo)=sum u >= 1, f(hi)=0; plus sum(u) for secant init
  float lo = 3.4e38f, hi = -3.4e38f, su = 0.f;
  #pragma unroll
  for (int t = 0; t < 16; ++t) {
    lo = fminf(lo, zf[t] - uf[t]);
    hi = fmaxf(hi, zf[t]);
    su += uf[t];
  }
  #pragma unroll
  for (int m = 32; m; m >>= 1) {
    lo = fminf(lo, __shfl_xor(lo, m));
    hi = fmaxf(hi, __shfl_xor(hi, m));
    su += __shfl_xor(su, m);
  }
  const double glo = (double)lo, ghi = (double)hi;

  // --- phase 1: f32 Newton (f via med3, C via ballot) ---
  float gl = su - 1.f, gh = -1.f;
  float tau = (lo * gh - hi * gl) / (gh - gl);       // secant init
  if (!(tau > lo && tau < hi)) tau = 0.5f * (lo + hi);
  for (int it = 0; it < 24; ++it) {
    float f0 = 0.f, f1 = 0.f, f2 = 0.f, f3 = 0.f;
    int C = 0;
    #pragma unroll
    for (int t = 0; t < 16; t += 4) {
      float xa = zf[t+0] - tau, xb = zf[t+1] - tau;
      float xc = zf[t+2] - tau, xd = zf[t+3] - tau;
      f0 += fminf(fmaxf(xa, 0.f), uf[t+0]);          // v_med3_f32
      f1 += fminf(fmaxf(xb, 0.f), uf[t+1]);
      f2 += fminf(fmaxf(xc, 0.f), uf[t+2]);
      f3 += fminf(fmaxf(xd, 0.f), uf[t+3]);
      C += (int)__popcll(__ballot(xa > 0.f && xa < uf[t+0]));
      C += (int)__popcll(__ballot(xb > 0.f && xb < uf[t+1]));
      C += (int)__popcll(__ballot(xc > 0.f && xc < uf[t+2]));
      C += (int)__popcll(__ballot(xd > 0.f && xd < uf[t+3]));
    }
    float g = wred((f0 + f1) + (f2 + f3)) - 1.f;
    if (g > 0.f) lo = tau; else hi = tau;
    float next;
    if (C > 0) {
      float cand = tau + g / (float)C;               // == (S-1)/C
      next = (cand > lo && cand < hi) ? cand : 0.5f * (lo + hi);
    } else {
      next = 0.5f * (lo + hi);
    }
    if (next == tau) break;                          // f32 fixed point
    tau = next;
  }

  // --- phase 2: f64 Newton polish on global bracket ---
  double dlo = glo, dhi = ghi, taud = (double)tau;
  for (int it = 0; it < 20; ++it) {
    double fd = 0.0;
    int C = 0;
    #pragma unroll
    for (int t = 0; t < 16; ++t) {
      double x = (double)zf[t] - taud;
      double ud = (double)uf[t];
      fd += fmin(fmax(x, 0.0), ud);
      C += (int)__popcll(__ballot(x > 0.0 && x < ud));
    }
    double g = wredd(fd) - 1.0;
    if (g == 0.0) break;                             // exact at f64 eval precision
    if (g > 0.0) dlo = taud; else dhi = taud;
    double next;
    if (C > 0) {
      double cand = taud + g / (double)C;            // segment root
      next = (cand > dlo && cand < dhi) ? cand : 0.5 * (dlo + dhi);
    } else {
      next = 0.5 * (dlo + dhi);
    }
    if (next == taud) break;                         // f64 fixed point
    taud = next;
  }
  return taud;
}

__device__ __forceinline__ void write_row(const float zf[16], const float uf[16],
                                          double taud, float* __restrict__ out,
                                          size_t base, int row, int lane, int B) {
  constexpr int K = 1024;
  float* out_p = out;
  float* out_r = out + (size_t)B * (size_t)K;
  float* out_t = out + 2ull * (size_t)B * (size_t)K;
  float* out_v = out_t + B;

  double vloc = 0.0;
  #pragma unroll
  for (int j = 0; j < 4; ++j) {
    float4 p4, r4;
    float pv[4], rv[4];
    #pragma unroll
    for (int q = 0; q < 4; ++q) {
      int t = j * 4 + q;
      double x = (double)zf[t] - taud;
      double ud = (double)uf[t];
      double p = x < 0.0 ? 0.0 : (x > ud ? ud : x);
      int reg = (p <= 0.0) ? 0 : ((p >= ud) ? 2 : 1);
      double d = p - (double)zf[t];
      vloc += d * d;
      pv[q] = (float)p;
      rv[q] = (float)reg;
    }
    p4.x = pv[0]; p4.y = pv[1]; p4.z = pv[2]; p4.w = pv[3];
    r4.x = rv[0]; r4.y = rv[1]; r4.z = rv[2]; r4.w = rv[3];
    ((float4*)(out_p + base))[j * 64 + lane] = p4;
    ((float4*)(out_r + base))[j * 64 + lane] = r4;
  }
  vloc = wredd(vloc);
  if (lane == 0) {
    out_t[row] = (float)taud;
    out_v[row] = (float)(0.5 * vloc);
  }
}

__global__ __launch_bounds__(256)
void csparsemax_kernel(const float* __restrict__ z, const float* __restrict__ u,
                       float* __restrict__ out, int B) {
  constexpr int K = 1024;
  const int lane = threadIdx.x & 63;
  const int wv = threadIdx.x >> 6;
  const int row0 = (blockIdx.x * 4 + wv) * 2;
  if (row0 >= B) return;
  const int row1 = row0 + 1;
  const size_t base0 = (size_t)row0 * (size_t)K;
  const size_t base1 = (size_t)row1 * (size_t)K;

  // Issue ALL loads up front: row1's 8 loads stay in flight (vmcnt>0)
  // under row0's compute; row0's stores drain under row1's compute.
  float zf0[16], uf0[16], zf1[16], uf1[16];
  {
    const float4* z0 = (const float4*)(z + base0);
    const float4* u0 = (const float4*)(u + base0);
    const float4* z1 = (const float4*)(z + base1);
    const float4* u1 = (const float4*)(u + base1);
    #pragma unroll
    for (int j = 0; j < 4; ++j) {
      float4 a = z0[j * 64 + lane];
      float4 b = u0[j * 64 + lane];
      zf0[j*4+0] = a.x; zf0[j*4+1] = a.y; zf0[j*4+2] = a.z; zf0[j*4+3] = a.w;
      uf0[j*4+0] = b.x; uf0[j*4+1] = b.y; uf0[j*4+2] = b.z; uf0[j*4+3] = b.w;
    }
    #pragma unroll
    for (int j = 0; j < 4; ++j) {
      float4 a = z1[j * 64 + lane];
      float4 b = u1[j * 64 + lane];
      zf1[j*4+0] = a.x; zf1[j*4+1] = a.y; zf1[j*4+2] = a.z; zf1[j*4+3] = a.w;
      uf1[j*4+0] = b.x; uf1[j*4+1] = b.y; uf1[j*4+2] = b.z; uf1[j*4+3] = b.w;
    }
  }

  double tau0 = solve_tau(zf0, uf0);
  write_row(zf0, uf0, tau0, out, base0, row0, lane, B);

  double tau1 = solve_tau(zf1, uf1);
  write_row(zf1, uf1, tau1, out, base1, row1, lane, B);
}

extern "C" void kernel_launch(void* const* d_in, const int* in_sizes, int n_in,
                              void* d_out, int out_size, void* d_ws, size_t ws_size,
                              hipStream_t stream) {
  const float* z = (const float*)d_in[0];
  const float* u = (const float*)d_in[1];
  float* out = (float*)d_out;
  const int K = 1024;
  const int B = in_sizes[0] / K;
  const int rows_per_block = 8;                      // 4 waves x 2 rows
  const int blocks = (B + rows_per_block - 1) / rows_per_block;
  csparsemax_kernel<<<blocks, 256, 0, stream>>>(z, u, out, B);
}

// Round 6
// 45.399 us; speedup vs baseline: 3.4164x; 3.4164x over previous
//
#include <hip/hip_runtime.h>

// Constrained sparsemax: p = clip(z - tau, 0, u), tau s.t. sum p = 1.
// R2 structure (best measured): one wave per row, 16 elems/lane in registers,
// segment-Newton with (S, C) reduced via two f32 __shfl_xor butterflies,
// f64 Newton polish for exactness. This round adds: secant init, f32 epilogue
// (f64 only for region-boundary compares), nontemporal output stores
// (via clang ext_vector_type -- HIP float4 is rejected by the builtin).

typedef float vfloat4 __attribute__((ext_vector_type(4)));

__global__ __launch_bounds__(256)
void csparsemax_kernel(const float* __restrict__ z, const float* __restrict__ u,
                       float* __restrict__ out, int B) {
  constexpr int K = 1024;
  const int lane = threadIdx.x & 63;
  const int wv = threadIdx.x >> 6;
  const int row = blockIdx.x * 4 + wv;
  if (row >= B) return;
  const size_t base = (size_t)row * (size_t)K;

  // --- load 16 elems/lane as 4x float4, coalesced ---
  float zf[16], uf[16];
  const vfloat4* z4p = (const vfloat4*)(z + base);
  const vfloat4* u4p = (const vfloat4*)(u + base);
  #pragma unroll
  for (int j = 0; j < 4; ++j) {
    vfloat4 a = z4p[j * 64 + lane];
    vfloat4 b = u4p[j * 64 + lane];
    zf[j*4+0] = a.x; zf[j*4+1] = a.y; zf[j*4+2] = a.z; zf[j*4+3] = a.w;
    uf[j*4+0] = b.x; uf[j*4+1] = b.y; uf[j*4+2] = b.z; uf[j*4+3] = b.w;
  }

  // --- bracket [lo,hi] + sum(u): f(lo)=sum u >= 1, f(hi)=0 ---
  float lo = 3.4e38f, hi = -3.4e38f, su = 0.f;
  #pragma unroll
  for (int t = 0; t < 16; ++t) {
    lo = fminf(lo, zf[t] - uf[t]);
    hi = fmaxf(hi, zf[t]);
    su += uf[t];
  }
  #pragma unroll
  for (int m = 32; m; m >>= 1) {
    lo = fminf(lo, __shfl_xor(lo, m));
    hi = fmaxf(hi, __shfl_xor(hi, m));
    su += __shfl_xor(su, m);
  }
  const double glo = (double)lo, ghi = (double)hi;

  // --- phase 1: f32 segment-Newton (R2's proven iteration) + secant init ---
  float tau = (lo + hi * (su - 1.f)) / su;          // secant through endpoints
  if (!(tau > lo && tau < hi)) tau = 0.5f * (lo + hi);
  for (int it = 0; it < 32; ++it) {
    float S0 = 0.f, S1 = 0.f, C0 = 0.f, C1 = 0.f;
    #pragma unroll
    for (int t = 0; t < 16; t += 2) {
      float xa = zf[t] - tau;
      float xb = zf[t+1] - tau;
      S0 += (xa >= uf[t])   ? uf[t]   : ((xa > 0.f) ? zf[t]   : 0.f);
      S1 += (xb >= uf[t+1]) ? uf[t+1] : ((xb > 0.f) ? zf[t+1] : 0.f);
      C0 += (xa > 0.f && xa < uf[t])   ? 1.f : 0.f;
      C1 += (xb > 0.f && xb < uf[t+1]) ? 1.f : 0.f;
    }
    float S = S0 + S1, C = C0 + C1;
    #pragma unroll
    for (int m = 32; m; m >>= 1) {
      S += __shfl_xor(S, m);
      C += __shfl_xor(C, m);
    }
    float f = S - C * tau;
    if (f > 1.f) lo = tau; else hi = tau;
    float next;
    if (C > 0.5f) {
      float cand = (S - 1.f) / C;                   // root of current segment
      if (cand == tau) break;                       // f32 fixed point
      next = (cand > lo && cand < hi) ? cand : 0.5f * (lo + hi);
    } else {
      next = 0.5f * (lo + hi);
    }
    if (next == tau) break;                         // bracket exhausted in f32
    tau = next;
  }

  // --- phase 2: f64 segment-Newton polish, global bracket ---
  double dlo = glo, dhi = ghi, taud = (double)tau;
  for (int it = 0; it < 24; ++it) {
    double S = 0.0;
    float Cf = 0.f;                                 // count is exact in f32
    #pragma unroll
    for (int t = 0; t < 16; ++t) {
      double x = (double)zf[t] - taud;
      double ud = (double)uf[t];
      if (x >= ud)      { S += ud; }
      else if (x > 0.0) { S += (double)zf[t]; Cf += 1.f; }
    }
    #pragma unroll
    for (int m = 32; m; m >>= 1) {
      S += __shfl_xor(S, m);
      Cf += __shfl_xor(Cf, m);
    }
    double C = (double)Cf;
    double f = S - C * taud;
    if (f == 1.0 && C > 0.5) break;
    if (f > 1.0) dlo = taud; else dhi = taud;
    double next;
    if (C > 0.5) {
      double cand = (S - 1.0) / C;                  // exact segment root
      if (cand == taud) break;
      next = (cand > dlo && cand < dhi) ? cand : 0.5 * (dlo + dhi);
    } else {
      next = 0.5 * (dlo + dhi);
    }
    if (next == taud) break;
    taud = next;
  }

  // --- epilogue: p/val in f32, regions decided by f64 compares ---
  float* out_p = out;
  float* out_r = out + (size_t)B * (size_t)K;
  float* out_t = out + 2ull * (size_t)B * (size_t)K;
  float* out_v = out_t + B;

  const float tf = (float)taud;
  float vloc = 0.f;
  #pragma unroll
  for (int j = 0; j < 4; ++j) {
    vfloat4 p4, r4;
    #pragma unroll
    for (int q = 0; q < 4; ++q) {
      int t = j * 4 + q;
      float pf = fminf(fmaxf(zf[t] - tf, 0.f), uf[t]);   // v_med3_f32
      float d = pf - zf[t];
      vloc = fmaf(d, d, vloc);
      double xd = (double)zf[t] - taud;                  // exact boundary tests
      float rg = (xd <= 0.0) ? 0.f : ((xd >= (double)uf[t]) ? 2.f : 1.f);
      p4[q] = pf;
      r4[q] = rg;
    }
    __builtin_nontemporal_store(p4, &((vfloat4*)(out_p + base))[j * 64 + lane]);
    __builtin_nontemporal_store(r4, &((vfloat4*)(out_r + base))[j * 64 + lane]);
  }

  #pragma unroll
  for (int m = 32; m; m >>= 1) vloc += __shfl_xor(vloc, m);
  if (lane == 0) {
    out_t[row] = tf;
    out_v[row] = 0.5f * vloc;
  }
}

extern "C" void kernel_launch(void* const* d_in, const int* in_sizes, int n_in,
                              void* d_out, int out_size, void* d_ws, size_t ws_size,
                              hipStream_t stream) {
  const float* z = (const float*)d_in[0];
  const float* u = (const float*)d_in[1];
  float* out = (float*)d_out;
  const int K = 1024;
  const int B = in_sizes[0] / K;
  const int blocks = (B + 3) / 4;
  csparsemax_kernel<<<blocks, 256, 0, stream>>>(z, u, out, B);
}

// Round 7
// 40.540 us; speedup vs baseline: 3.8259x; 1.1199x over previous
//
#include <hip/hip_runtime.h>

// Constrained sparsemax: p = clip(z - tau, 0, u), tau s.t. sum p = 1.
// R6 structure (wave-per-row, f32 segment-Newton + f64 polish, NT stores),
// with ALL cross-lane reductions converted from __shfl_xor (ds_bpermute,
// LDS-pipe latency) to DPP row_shr/row_bcast chains (pure VALU) ending in
// readlane(63) -> wave-uniform SGPR values for the iteration decisions.

typedef float vfloat4 __attribute__((ext_vector_type(4)));

template<int CTRL>
__device__ __forceinline__ float dpp_zero(float v) {   // invalid lanes -> 0
  return __builtin_bit_cast(float,
    __builtin_amdgcn_update_dpp(0, __builtin_bit_cast(int, v), CTRL, 0xf, 0xf, true));
}
template<int CTRL>
__device__ __forceinline__ float dpp_ident(float v, float ident) { // invalid -> ident
  return __builtin_bit_cast(float,
    __builtin_amdgcn_update_dpp(__builtin_bit_cast(int, ident),
                                __builtin_bit_cast(int, v), CTRL, 0xf, 0xf, false));
}

__device__ __forceinline__ float wave_sum(float v) {   // uniform full-wave sum
  v += dpp_zero<0x111>(v);   // row_shr:1
  v += dpp_zero<0x112>(v);   // row_shr:2
  v += dpp_zero<0x114>(v);   // row_shr:4
  v += dpp_zero<0x118>(v);   // row_shr:8
  v += dpp_zero<0x142>(v);   // row_bcast:15
  v += dpp_zero<0x143>(v);   // row_bcast:31
  return __builtin_bit_cast(float,
    __builtin_amdgcn_readlane(__builtin_bit_cast(int, v), 63));
}

__device__ __forceinline__ float wave_max(float v) {   // uniform full-wave max
  const float NI = -3.4028235e38f;
  v = fmaxf(v, dpp_ident<0x111>(v, NI));
  v = fmaxf(v, dpp_ident<0x112>(v, NI));
  v = fmaxf(v, dpp_ident<0x114>(v, NI));
  v = fmaxf(v, dpp_ident<0x118>(v, NI));
  v = fmaxf(v, dpp_ident<0x142>(v, NI));
  v = fmaxf(v, dpp_ident<0x143>(v, NI));
  return __builtin_bit_cast(float,
    __builtin_amdgcn_readlane(__builtin_bit_cast(int, v), 63));
}

__device__ __forceinline__ double wave_sumd(double v) { // uniform f64 sum
  #define DPP_F64_STEP(CTRL)                                                   \
  { unsigned long long x = __builtin_bit_cast(unsigned long long, v);          \
    int l_ = __builtin_amdgcn_update_dpp(0, (int)(unsigned)x, CTRL, 0xf, 0xf, true); \
    int h_ = __builtin_amdgcn_update_dpp(0, (int)(x >> 32),   CTRL, 0xf, 0xf, true); \
    v += __builtin_bit_cast(double,                                            \
      ((unsigned long long)(unsigned)h_ << 32) | (unsigned)l_); }
  DPP_F64_STEP(0x111) DPP_F64_STEP(0x112) DPP_F64_STEP(0x114)
  DPP_F64_STEP(0x118) DPP_F64_STEP(0x142) DPP_F64_STEP(0x143)
  #undef DPP_F64_STEP
  unsigned long long x = __builtin_bit_cast(unsigned long long, v);
  int l_ = __builtin_amdgcn_readlane((int)(unsigned)x, 63);
  int h_ = __builtin_amdgcn_readlane((int)(x >> 32), 63);
  return __builtin_bit_cast(double,
    ((unsigned long long)(unsigned)h_ << 32) | (unsigned)l_);
}

__global__ __launch_bounds__(256)
void csparsemax_kernel(const float* __restrict__ z, const float* __restrict__ u,
                       float* __restrict__ out, int B) {
  constexpr int K = 1024;
  const int lane = threadIdx.x & 63;
  const int wv = threadIdx.x >> 6;
  const int row = blockIdx.x * 4 + wv;
  if (row >= B) return;
  const size_t base = (size_t)row * (size_t)K;

  // --- load 16 elems/lane as 4x float4, coalesced ---
  float zf[16], uf[16];
  const vfloat4* z4p = (const vfloat4*)(z + base);
  const vfloat4* u4p = (const vfloat4*)(u + base);
  #pragma unroll
  for (int j = 0; j < 4; ++j) {
    vfloat4 a = z4p[j * 64 + lane];
    vfloat4 b = u4p[j * 64 + lane];
    zf[j*4+0] = a.x; zf[j*4+1] = a.y; zf[j*4+2] = a.z; zf[j*4+3] = a.w;
    uf[j*4+0] = b.x; uf[j*4+1] = b.y; uf[j*4+2] = b.z; uf[j*4+3] = b.w;
  }

  // --- bracket [lo,hi] + sum(u): f(lo)=sum u >= 1, f(hi)=0 ---
  float mzu = -3.4028235e38f, mz = -3.4028235e38f, sup = 0.f;
  #pragma unroll
  for (int t = 0; t < 16; ++t) {
    mzu = fmaxf(mzu, uf[t] - zf[t]);   // lo = -max(u-z) = min(z-u)
    mz  = fmaxf(mz, zf[t]);
    sup += uf[t];
  }
  float lo = -wave_max(mzu);
  float hi = wave_max(mz);
  const float su = wave_sum(sup);
  const double glo = (double)lo, ghi = (double)hi;

  // --- phase 1: f32 segment-Newton, secant init ---
  float tau = (lo + hi * (su - 1.f)) / su;
  if (!(tau > lo && tau < hi)) tau = 0.5f * (lo + hi);
  for (int it = 0; it < 32; ++it) {
    float S0 = 0.f, S1 = 0.f, C0 = 0.f, C1 = 0.f;
    #pragma unroll
    for (int t = 0; t < 16; t += 2) {
      float xa = zf[t] - tau;
      float xb = zf[t+1] - tau;
      S0 += (xa >= uf[t])   ? uf[t]   : ((xa > 0.f) ? zf[t]   : 0.f);
      S1 += (xb >= uf[t+1]) ? uf[t+1] : ((xb > 0.f) ? zf[t+1] : 0.f);
      C0 += (xa > 0.f && xa < uf[t])   ? 1.f : 0.f;
      C1 += (xb > 0.f && xb < uf[t+1]) ? 1.f : 0.f;
    }
    float S = wave_sum((S0 + S1) + (C0 * 0.f + S1 * 0.f) + S0 * 0.f);  // placeholder avoided below
    // (compute separately to keep two independent DPP chains)
    S = wave_sum(S0 + S1);
    float C = wave_sum(C0 + C1);
    float f = S - C * tau;
    if (f > 1.f) lo = tau; else hi = tau;
    float next;
    if (C > 0.5f) {
      float cand = (S - 1.f) / C;
      if (cand == tau) break;
      next = (cand > lo && cand < hi) ? cand : 0.5f * (lo + hi);
    } else {
      next = 0.5f * (lo + hi);
    }
    if (next == tau) break;
    tau = next;
  }

  // --- phase 2: f64 segment-Newton polish, global bracket ---
  double dlo = glo, dhi = ghi, taud = (double)tau;
  for (int it = 0; it < 24; ++it) {
    double Sd = 0.0;
    float Cf = 0.f;
    #pragma unroll
    for (int t = 0; t < 16; ++t) {
      double x = (double)zf[t] - taud;
      double ud = (double)uf[t];
      if (x >= ud)      { Sd += ud; }
      else if (x > 0.0) { Sd += (double)zf[t]; Cf += 1.f; }
    }
    double S = wave_sumd(Sd);
    double C = (double)wave_sum(Cf);
    double f = S - C * taud;
    if (f == 1.0 && C > 0.5) break;
    if (f > 1.0) dlo = taud; else dhi = taud;
    double next;
    if (C > 0.5) {
      double cand = (S - 1.0) / C;
      if (cand == taud) break;
      next = (cand > dlo && cand < dhi) ? cand : 0.5 * (dlo + dhi);
    } else {
      next = 0.5 * (dlo + dhi);
    }
    if (next == taud) break;
    taud = next;
  }

  // --- epilogue: p/val in f32, regions via f64 compares, NT stores ---
  float* out_p = out;
  float* out_r = out + (size_t)B * (size_t)K;
  float* out_t = out + 2ull * (size_t)B * (size_t)K;
  float* out_v = out_t + B;

  const float tf = (float)taud;
  float vloc = 0.f;
  #pragma unroll
  for (int j = 0; j < 4; ++j) {
    vfloat4 p4, r4;
    #pragma unroll
    for (int q = 0; q < 4; ++q) {
      int t = j * 4 + q;
      float pf = fminf(fmaxf(zf[t] - tf, 0.f), uf[t]);   // v_med3_f32
      float d = pf - zf[t];
      vloc = fmaf(d, d, vloc);
      double xd = (double)zf[t] - taud;
      float rg = (xd <= 0.0) ? 0.f : ((xd >= (double)uf[t]) ? 2.f : 1.f);
      p4[q] = pf;
      r4[q] = rg;
    }
    __builtin_nontemporal_store(p4, &((vfloat4*)(out_p + base))[j * 64 + lane]);
    __builtin_nontemporal_store(r4, &((vfloat4*)(out_r + base))[j * 64 + lane]);
  }

  float vtot = wave_sum(vloc);
  if (lane == 0) {
    out_t[row] = tf;
    out_v[row] = 0.5f * vtot;
  }
}

extern "C" void kernel_launch(void* const* d_in, const int* in_sizes, int n_in,
                              void* d_out, int out_size, void* d_ws, size_t ws_size,
                              hipStream_t stream) {
  const float* z = (const float*)d_in[0];
  const float* u = (const float*)d_in[1];
  float* out = (float*)d_out;
  const int K = 1024;
  const int B = in_sizes[0] / K;
  const int blocks = (B + 3) / 4;
  csparsemax_kernel<<<blocks, 256, 0, stream>>>(z, u, out, B);
}